// Round 14
// baseline (670.554 us; speedup 1.0000x reference)
//
#include <hip/hip_runtime.h>
#include <stdint.h>

typedef unsigned short u16;
typedef short bf16x8 __attribute__((ext_vector_type(8)));
typedef float f32x4 __attribute__((ext_vector_type(4)));
typedef unsigned short u16x4 __attribute__((ext_vector_type(4)));

#define NB   256
#define NS   200
#define NHID 768
#define NHEAD 12
#define NDK  64
#define NK   64
#define NBH  (NB*NHEAD)   // 3072
#define NM   (NB*NS)      // 51200

__device__ __forceinline__ u16 f2b(float f){
  unsigned u = __builtin_bit_cast(unsigned, f);
  return (u16)((u + 0x7FFFu + ((u>>16)&1u)) >> 16);   // RNE, finite inputs
}
__device__ __forceinline__ float b2f(u16 b){
  return __builtin_bit_cast(float, (unsigned)b << 16);
}
__device__ __forceinline__ bf16x8 pack8(const float* v){
  bf16x8 r;
#pragma unroll
  for (int i=0;i<8;i++) r[i] = (short)f2b(v[i]);
  return r;
}
__device__ __forceinline__ f32x4 mfma16(bf16x8 a, bf16x8 b, f32x4 c){
  return __builtin_amdgcn_mfma_f32_16x16x32_bf16(a, b, c, 0, 0, 0);
}
__device__ __forceinline__ void gload16(u16* l, const u16* g){
  __builtin_amdgcn_global_load_lds(
      (const __attribute__((address_space(1))) void*)g,
      (__attribute__((address_space(3))) void*)l, 16, 0, 0);
}

// ---------------- K0: merged prep (pack W's, pack Wfe[128][256], rowsums) ----
__global__ __launch_bounds__(256) void prep_kernel(
    const float* __restrict__ Wq, const float* __restrict__ Wk,
    const float* __restrict__ Wv, const float* __restrict__ Wd,
    const float* __restrict__ Wf, const float* __restrict__ We,
    const float* __restrict__ mask,
    u16* __restrict__ Wqb, u16* __restrict__ Wkb,
    u16* __restrict__ Wvb, u16* __restrict__ Wdb,
    u16* __restrict__ Wfeb, float* __restrict__ rs)
{
  const int blk = blockIdx.x, t = threadIdx.x;
  const int i = blk*256 + t;            // grid 2304 -> 589824 exact
  Wqb[i]=f2b(Wq[i]); Wkb[i]=f2b(Wk[i]); Wvb[i]=f2b(Wv[i]); Wdb[i]=f2b(Wd[i]);
  if (blk < 128){                       // Wfe pack: row=blk, 256 cols (200 real)
    float v = 0.f;
    if (t < NS) v = (blk<64) ? Wf[blk*NS+t] : We[(blk-64)*NS+t];
    Wfeb[blk*256+t] = f2b(v);
  }
  if (blk >= 1024 && blk < 1280 && t < 128){  // rowsums: b=blk-1024, kk=t
    const int b = blk-1024;
    const float* src = (t<64) ? (Wf + t*NS) : (We + (t-64)*NS);
    float acc = 0.f;
    for (int s=0;s<NS;s++) acc += src[s]*mask[b*NS+s];
    rs[b*128+t] = acc;
  }
}

// ---------------- K2: yfe = Wfe_masked @ x[b]^T, FUSED x->xb convert ---------
__global__ __launch_bounds__(256) void gemm_yfe2(
    const float* __restrict__ x, const float* __restrict__ mask,
    const u16* __restrict__ Wfeb, u16* __restrict__ yfe,
    u16* __restrict__ xb)
{
  __shared__ u16 Al[128*64];     // A K-slice, ld=64
  __shared__ u16 Bl[128*72];     // B K-slice, ld=72, swizzled
  __shared__ float Ml[256];      // mask row, zero-extended
  const int t=threadIdx.x, w=t>>6, lane=t&63, hi=lane>>4, lo=lane&15;
  const int sr=lane>>3, sc=lane&7;
  const int b=blockIdx.x, col0=blockIdx.y*128;
  const int a16 = t&15, q4 = t>>4;
  const int ss0 = q4*4;
  const int swzw = (a16&7)<<3;

  Ml[t] = (t<NS) ? mask[b*NS+t] : 0.f;

  f32x4 acc[4][4];
#pragma unroll
  for(int i=0;i<4;i++)
#pragma unroll
    for(int j=0;j<4;j++) acc[i][j]=(f32x4)0.0f;

  const u16* Ab=&Al[((w>>1)*64+lo)*64 + hi*8];
  int nb_[4], sw_[4];
#pragma unroll
  for (int j=0;j<4;j++){
    const int n = (w&1)*64 + j*16 + lo;
    nb_[j] = n*72;
    sw_[j] = ((n>>3)&7)<<3;
  }
  __syncthreads();   // Ml visible

  for (int kt=0; kt<256; kt+=64){
#pragma unroll
    for (int i8=0;i8<4;i8++){
      const int r = w*32 + i8*8 + sr;
      gload16(&Al[r*64 + sc*8], Wfeb + (size_t)r*256 + kt + sc*8);
    }
    float vv[4][8];
#pragma unroll
    for (int ii=0;ii<4;ii++){
      const int s = kt + ss0 + ii;
      const int srow = (s<NS) ? s : (NS-1);
      const float* gp = x + ((size_t)b*NS + srow)*NHID + col0 + a16*8;
      float4 u0 = *(const float4*)gp, u1 = *(const float4*)(gp+4);
      if (s < NS){
        float tu[8] = {u0.x,u0.y,u0.z,u0.w,u1.x,u1.y,u1.z,u1.w};
        *(bf16x8*)(xb + ((size_t)b*NS + s)*NHID + col0 + a16*8) = pack8(tu);
      }
      const float m = Ml[s];
      vv[ii][0]=u0.x*m; vv[ii][1]=u0.y*m; vv[ii][2]=u0.z*m; vv[ii][3]=u0.w*m;
      vv[ii][4]=u1.x*m; vv[ii][5]=u1.y*m; vv[ii][6]=u1.z*m; vv[ii][7]=u1.w*m;
    }
    const int ss_swz = ss0 ^ swzw;
#pragma unroll
    for (int h=0;h<8;h++){
      u16x4 p;
      p[0]=f2b(vv[0][h]); p[1]=f2b(vv[1][h]);
      p[2]=f2b(vv[2][h]); p[3]=f2b(vv[3][h]);
      *(u16x4*)&Bl[(a16*8+h)*72 + ss_swz] = p;
    }
    asm volatile("s_waitcnt vmcnt(0)" ::: "memory");
    __syncthreads();
#pragma unroll
    for (int ks=0; ks<2; ks++){
      bf16x8 a[4], bfr[4];
#pragma unroll
      for (int i=0;i<4;i++) a[i]   = *(const bf16x8*)(Ab + i*16*64 + ks*32);
#pragma unroll
      for (int j=0;j<4;j++){
        const int s8 = ks*32 + hi*8;
        bfr[j] = *(const bf16x8*)&Bl[nb_[j] + (s8 ^ sw_[j])];
      }
#pragma unroll
      for (int i=0;i<4;i++)
#pragma unroll
        for (int j=0;j<4;j++) acc[i][j] = mfma16(a[i], bfr[j], acc[i][j]);
    }
    __syncthreads();
  }
  const int mbase=(w>>1)*64, nbase=col0+(w&1)*64;
#pragma unroll
  for (int i=0;i<4;i++)
#pragma unroll
    for (int r=0;r<4;r++){
      const int m = mbase + i*16 + hi*4 + r;
#pragma unroll
      for (int j=0;j<4;j++){
        const int n = nbase + j*16 + lo;
        yfe[(size_t)b*98304 + (size_t)m*NHID + n] = f2b(acc[i][j][r]);
      }
    }
}

// ---------------- ring GEMM (EPI=1 only): h = ctx @ Wd^T + bd + xb -----------
__global__ __launch_bounds__(512, 2) void gemm_ring(
    const u16* __restrict__ Ag_, const u16* __restrict__ Bg_,
    const float* __restrict__ bias, const u16* __restrict__ resid,
    u16* __restrict__ Cout)
{
  __shared__ u16 AS[4][8192];
  __shared__ u16 BS[4][8192];
  const int t = threadIdx.x;
  const int w = t>>6, lane = t&63, hi = lane>>4, lo = lane&15;
  const int wm = w>>2, wn = w&3;
  const int bid = blockIdx.x;
  const int row0 = ((bid/24)*8 + (bid&7))*256;    // bijective: 600 = 25*24
  const int col0 = ((bid>>3)%3)*256;
  const u16* Ag = Ag_ + (size_t)row0*NHID;
  const u16* Bg = Bg_ + (size_t)col0*NHID;
  const int rp0 = t>>3, cc = t&7;

  f32x4 acc[8][4];
#pragma unroll
  for (int i=0;i<8;i++)
#pragma unroll
    for (int j=0;j<4;j++) acc[i][j] = (f32x4)0.0f;

  int aoff[8], boff[4];
#pragma unroll
  for (int i=0;i<8;i++){
    const int r = wm*128 + i*16 + lo;
    const int rp = r>>1, c = (r&1)*4 + hi;
    aoff[i] = rp*64 + ((c ^ (rp&7))<<3);
  }
#pragma unroll
  for (int j=0;j<4;j++){
    const int n = wn*64 + j*16 + lo;
    const int rp = n>>1, c = (n&1)*4 + hi;
    boff[j] = rp*64 + ((c ^ (rp&7))<<3);
  }

  auto stage = [&](int s, int kt){
#pragma unroll
    for (int i8=0;i8<2;i8++){
      const int rp = i8*64 + rp0;
      const int c  = cc ^ (rp&7);
      const int grow = rp*2 + (c>>2);
      const int gcol = (c&3)<<3;
      gload16(&AS[s][rp*64 + cc*8], Ag + (size_t)grow*NHID + kt + gcol);
      gload16(&BS[s][rp*64 + cc*8], Bg + (size_t)grow*NHID + kt + gcol);
    }
  };
  auto body = [&](const u16* as_, const u16* bs_){
    bf16x8 av[8], bvv[4];
#pragma unroll
    for (int j=0;j<4;j++) bvv[j] = *(const bf16x8*)(bs_ + boff[j]);
#pragma unroll
    for (int i=0;i<8;i++) av[i] = *(const bf16x8*)(as_ + aoff[i]);
    __builtin_amdgcn_s_setprio(1);
#pragma unroll
    for (int i=0;i<8;i++)
#pragma unroll
      for (int j=0;j<4;j++) acc[i][j] = mfma16(av[i], bvv[j], acc[i][j]);
    __builtin_amdgcn_s_setprio(0);
  };
  auto step = [&](int tt, int s){
    if (tt+3 < 24) stage((s+3)&3, (tt+3)*32);
    body(AS[s], BS[s]);
    if (tt <= 20)      { asm volatile("s_waitcnt vmcnt(8)" ::: "memory"); }
    else if (tt == 21) { asm volatile("s_waitcnt vmcnt(4)" ::: "memory"); }
    else if (tt == 22) { asm volatile("s_waitcnt vmcnt(0)" ::: "memory"); }
    if (tt < 23){
      __builtin_amdgcn_sched_barrier(0);
      asm volatile("s_barrier" ::: "memory");
      __builtin_amdgcn_sched_barrier(0);
    }
  };

  stage(0,0); stage(1,32); stage(2,64);
  asm volatile("s_waitcnt vmcnt(8)" ::: "memory");
  asm volatile("s_barrier" ::: "memory");
  __builtin_amdgcn_sched_barrier(0);

#pragma unroll
  for (int tt=0; tt<24; tt+=4){
    step(tt,0); step(tt+1,1); step(tt+2,2); step(tt+3,3);
  }

#pragma unroll
  for (int i=0;i<8;i++)
#pragma unroll
    for (int q=0;q<4;q++){
      const int m = row0 + wm*128 + i*16 + hi*4 + q;
#pragma unroll
      for (int j=0;j<4;j++){
        const int n = col0 + wn*64 + j*16 + lo;
        const size_t gi = (size_t)m*NHID + n;
        Cout[gi] = f2b(acc[i][j][q] + bias[n] + b2f(resid[gi]));
      }
    }
}

// ---------------- K4: merged kproj (z=0) / vprojT (z=1) ----------------------
__global__ __launch_bounds__(256) void gemm_projkv(
    const u16* __restrict__ yfe, const u16* __restrict__ Wkb,
    const u16* __restrict__ Wvb, const float* __restrict__ rs,
    const float* __restrict__ bk, const float* __restrict__ bv,
    const float* __restrict__ bff, const float* __restrict__ bee,
    u16* __restrict__ kproj, u16* __restrict__ vout)
{
  __shared__ u16 S[192*64];
  const int t=threadIdx.x, w=t>>6, lane=t&63, hi=lane>>4, lo=lane&15;
  const int sr=lane>>3, sc=lane&7;
  const int bid=blockIdx.x;
  const int b = (bid/96)*8 + (bid&7);             // bijective: 3072 = 32*96
  const int jj = (bid>>3)%12;
  const int colb = jj%6, z = jj/6;

  if (z==0){
    u16* Al = S;                 // 64x64
    u16* Bl = S + 64*64;         // 128x64
    const int col0=colb*128;
    const u16* yf = yfe + (size_t)b*98304;
    f32x4 acc[2][4];
#pragma unroll
    for(int i=0;i<2;i++)
#pragma unroll
      for(int j=0;j<4;j++) acc[i][j]=(f32x4)0.0f;
    const u16* Ab=&Al[((w>>1)*32+lo)*64 + hi*8];
    const u16* Bb=&Bl[((w&1)*64+lo)*64 + hi*8];
    for (int kt=0; kt<NHID; kt+=64){
#pragma unroll
      for (int i8=0;i8<2;i8++){
        const int r = w*16 + i8*8 + sr;
        gload16(&Al[r*64 + sc*8], yf + (size_t)r*NHID + kt + sc*8);
      }
#pragma unroll
      for (int i8=0;i8<4;i8++){
        const int r = w*32 + i8*8 + sr;
        gload16(&Bl[r*64 + sc*8], Wkb + (size_t)(col0+r)*NHID + kt + sc*8);
      }
      asm volatile("s_waitcnt vmcnt(0)" ::: "memory");
      __syncthreads();
#pragma unroll
      for (int ks=0; ks<2; ks++){
        bf16x8 a[2], bfr[4];
#pragma unroll
        for (int i=0;i<2;i++) a[i]   = *(const bf16x8*)(Ab + i*16*64 + ks*32);
#pragma unroll
        for (int j=0;j<4;j++) bfr[j] = *(const bf16x8*)(Bb + j*16*64 + ks*32);
#pragma unroll
        for (int i=0;i<2;i++)
#pragma unroll
          for (int j=0;j<4;j++) acc[i][j] = mfma16(a[i], bfr[j], acc[i][j]);
      }
      __syncthreads();
    }
    const int mbase=(w>>1)*32, nbase=col0+(w&1)*64;
#pragma unroll
    for (int i=0;i<2;i++)
#pragma unroll
      for (int r=0;r<4;r++){
        const int m = mbase + i*16 + hi*4 + r;          // kk
        const float rsv = rs[b*128 + m], bfv = bff[m];
#pragma unroll
        for (int j=0;j<4;j++){
          const int n = nbase + j*16 + lo;              // hd
          kproj[(size_t)b*49152 + (size_t)m*NHID + n] = f2b(acc[i][j][r] + rsv*bk[n] + bfv);
        }
      }
  } else {
    u16* Al = S;                 // 128x64
    u16* Bl = S + 128*64;        // 64x64
    const int row0=colb*128;
    const u16* ye = yfe + (size_t)b*98304 + 49152;
    f32x4 acc[4][2];
#pragma unroll
    for(int i=0;i<4;i++)
#pragma unroll
      for(int j=0;j<2;j++) acc[i][j]=(f32x4)0.0f;
    const u16* Ab=&Al[((w>>1)*64+lo)*64 + hi*8];
    const u16* Bb=&Bl[((w&1)*32+lo)*64 + hi*8];
    for (int kt=0; kt<NHID; kt+=64){
#pragma unroll
      for (int i8=0;i8<4;i8++){
        const int r = w*32 + i8*8 + sr;
        gload16(&Al[r*64 + sc*8], Wvb + (size_t)(row0+r)*NHID + kt + sc*8);
      }
#pragma unroll
      for (int i8=0;i8<2;i8++){
        const int r = w*16 + i8*8 + sr;
        gload16(&Bl[r*64 + sc*8], ye + (size_t)r*NHID + kt + sc*8);
      }
      asm volatile("s_waitcnt vmcnt(0)" ::: "memory");
      __syncthreads();
#pragma unroll
      for (int ks=0; ks<2; ks++){
        bf16x8 a[4], bfr[2];
#pragma unroll
        for (int i=0;i<4;i++) a[i]   = *(const bf16x8*)(Ab + i*16*64 + ks*32);
#pragma unroll
        for (int j=0;j<2;j++) bfr[j] = *(const bf16x8*)(Bb + j*16*64 + ks*32);
#pragma unroll
        for (int i=0;i<4;i++)
#pragma unroll
          for (int j=0;j<2;j++) acc[i][j] = mfma16(a[i], bfr[j], acc[i][j]);
      }
      __syncthreads();
    }
    const int mbase=row0+(w>>1)*64, nbase=(w&1)*32;
#pragma unroll
    for (int i=0;i<4;i++)
#pragma unroll
      for (int r=0;r<4;r++){
        const int m = mbase + i*16 + hi*4 + r;          // hd
        const float bvv = bv[m];
#pragma unroll
        for (int j=0;j<2;j++){
          const int n = nbase + j*16 + lo;              // kk
          vout[(size_t)b*49152 + (size_t)m*64 + n] = f2b(acc[i][j][r] + rs[b*128+64+n]*bvv + bee[n]);
        }
      }
  }
}

// ---------------- K5: fused q-proj + attention per (b,h) ---------------------
// Phase 1: q = xb[b] @ Wq[h]^T + bq  (BK=32, XA/WB ld=40, aliased over KP/VP)
// Phase 2: scores -> softmax -> p_attn out + P->QL -> ctx = P @ vproj
// XCD swizzle: 12 head-blocks of a b share the XCD -> xb[b] (300KB) L2-hits.
__global__ __launch_bounds__(256) void attn2_kernel(
    const u16* __restrict__ xb,      // [B][200][768]
    const u16* __restrict__ Wqb,     // [768][768]
    const float* __restrict__ bq,    // [768]
    const u16* __restrict__ kproj,   // [B][64][768]  ([kk][h*64+d])
    const u16* __restrict__ vprojT,  // [B][768][64]  ([h*64+d][kk])
    float* __restrict__ pout,        // [BH][200][64] fp32
    u16* __restrict__ ctxb)          // [B][200][768] bf16
{
  __shared__ u16 SH[25856];          // 51,712 B -> 3 blocks/CU
  u16* QL = SH;                      // [208][72]
  u16* XA = SH + 14976;              // [208][40]  (q-phase scratch)
  u16* WB = SH + 23296;              // [64][40]
  u16* KP = SH + 14976;              // [64][72]   (aliases XA after q-phase)
  u16* VP = SH + 19584;              // [64][72]
  const int t=threadIdx.x, w=t>>6, lane=t&63, hi=lane>>4, lo=lane&15;
  const int bid=blockIdx.x;
  const int b  = (bid/96)*8 + (bid&7);   // bijective: 3072 = 32*96
  const int hh = (bid>>3)%12;
  const int bh = b*NHEAD + hh;
  const int mf0 = (w==0)?0:(1+w*3);
  const int nmf = (w==0)?4:3;

  // ---- Phase 1: q-projection ----
  f32x4 acc[4][4];
#pragma unroll
  for(int i=0;i<4;i++)
#pragma unroll
    for(int j=0;j<4;j++) acc[i][j]=(f32x4)0.0f;

  for (int kt=0; kt<NHID; kt+=32){
    for (int c=t; c<832; c+=256){            // XA: 208 rows x 32 k
      const int row=c>>2, col8=(c&3)*8;
      const int srow = (row<NS) ? row : (NS-1);
      *(bf16x8*)&XA[row*40+col8] =
        *(const bf16x8*)(xb + ((size_t)b*NS+srow)*NHID + kt + col8);
    }
    {                                        // WB: 64 rows x 32 k
      const int row=t>>2, col8=(t&3)*8;
      *(bf16x8*)&WB[row*40+col8] =
        *(const bf16x8*)(Wqb + (size_t)(hh*64+row)*NHID + kt + col8);
    }
    __syncthreads();
    bf16x8 a[4], bbf[4];
#pragma unroll
    for (int j=0;j<4;j++) bbf[j] = *(const bf16x8*)&WB[(j*16+lo)*40 + hi*8];
#pragma unroll
    for (int i=0;i<4;i++) if (i<nmf) a[i] = *(const bf16x8*)&XA[((mf0+i)*16+lo)*40 + hi*8];
#pragma unroll
    for (int i=0;i<4;i++) if (i<nmf)
#pragma unroll
      for (int j=0;j<4;j++) acc[i][j] = mfma16(a[i], bbf[j], acc[i][j]);
    __syncthreads();
  }
  {
    float bq_[4];
#pragma unroll
    for (int j=0;j<4;j++) bq_[j] = bq[hh*64 + j*16 + lo];
#pragma unroll
    for (int i=0;i<4;i++) if (i<nmf)
#pragma unroll
      for (int r=0;r<4;r++){
        const int q = (mf0+i)*16 + hi*4 + r;
#pragma unroll
        for (int j=0;j<4;j++)
          QL[q*72 + j*16 + lo] = f2b(acc[i][j][r] + bq_[j]);
      }
  }
  __syncthreads();   // QL complete; XA/WB dead -> stage KP/VP into alias
  for (int c=t;c<512;c+=256){
    const int row=c>>3, col8=(c&7)*8;
    *(bf16x8*)&KP[row*72+col8] = *(const bf16x8*)(kproj  + (size_t)b*49152 + (size_t)row*NHID + hh*64 + col8);
    *(bf16x8*)&VP[row*72+col8] = *(const bf16x8*)(vprojT + (size_t)b*49152 + (size_t)(hh*64+row)*64 + col8);
  }
  __syncthreads();

  // ---- Phase 2: scores / softmax / PV (R13 structure) ----
#pragma unroll
  for(int i=0;i<4;i++)
#pragma unroll
    for(int j=0;j<4;j++) acc[i][j]=(f32x4)0.0f;
#pragma unroll
  for (int ks=0; ks<2; ks++){
    bf16x8 a[4], bb[4];
#pragma unroll
    for (int j=0;j<4;j++) bb[j]=*(const bf16x8*)&KP[(j*16+lo)*72 + ks*32 + hi*8];
#pragma unroll
    for (int i=0;i<4;i++) if (i<nmf) a[i]=*(const bf16x8*)&QL[((mf0+i)*16+lo)*72 + ks*32 + hi*8];
#pragma unroll
    for (int i=0;i<4;i++) if (i<nmf)
#pragma unroll
      for (int j=0;j<4;j++)
        acc[i][j]=mfma16(a[i],bb[j],acc[i][j]);
  }
  __syncthreads();

#pragma unroll
  for (int i=0;i<4;i++) if (i<nmf){
#pragma unroll
    for (int r=0;r<4;r++){
      const int q = (mf0+i)*16 + hi*4 + r;
      float s0=acc[i][0][r]*0.125f, s1=acc[i][1][r]*0.125f,
            s2=acc[i][2][r]*0.125f, s3=acc[i][3][r]*0.125f;
      float mx=fmaxf(fmaxf(s0,s1),fmaxf(s2,s3));
      mx=fmaxf(mx,__shfl_xor(mx,1)); mx=fmaxf(mx,__shfl_xor(mx,2));
      mx=fmaxf(mx,__shfl_xor(mx,4)); mx=fmaxf(mx,__shfl_xor(mx,8));
      float e0=__expf(s0-mx), e1=__expf(s1-mx), e2=__expf(s2-mx), e3=__expf(s3-mx);
      float sm=e0+e1+e2+e3;
      sm+=__shfl_xor(sm,1); sm+=__shfl_xor(sm,2); sm+=__shfl_xor(sm,4); sm+=__shfl_xor(sm,8);
      const float inv=1.0f/sm;
      const float p0=e0*inv,p1=e1*inv,p2=e2*inv,p3=e3*inv;
      if (q<NS){
        float* pg = pout + ((size_t)bh*NS + q)*NK + lo;
        pg[0]=p0; pg[16]=p1; pg[32]=p2; pg[48]=p3;
      }
      u16* pl = &QL[q*72 + lo];
      pl[0]=f2b(p0); pl[16]=f2b(p1); pl[32]=f2b(p2); pl[48]=f2b(p3);
    }
  }
  f32x4 acc2[4][4];
#pragma unroll
  for(int i=0;i<4;i++)
#pragma unroll
    for(int j=0;j<4;j++) acc2[i][j]=(f32x4)0.0f;
#pragma unroll
  for (int ks=0; ks<2; ks++){
    bf16x8 a[4], bb[4];
#pragma unroll
    for (int j=0;j<4;j++) bb[j]=*(const bf16x8*)&VP[(j*16+lo)*72 + ks*32 + hi*8];
#pragma unroll
    for (int i=0;i<4;i++) if (i<nmf) a[i]=*(const bf16x8*)&QL[((mf0+i)*16+lo)*72 + ks*32 + hi*8];
#pragma unroll
    for (int i=0;i<4;i++) if (i<nmf)
#pragma unroll
      for (int j=0;j<4;j++)
        acc2[i][j]=mfma16(a[i],bb[j],acc2[i][j]);
  }
#pragma unroll
  for (int i=0;i<4;i++) if (i<nmf)
#pragma unroll
    for (int r=0;r<4;r++){
      const int q=(mf0+i)*16+hi*4+r;
      if (q<NS){
#pragma unroll
        for (int j=0;j<4;j++){
          const int d=j*16+lo;
          ctxb[((size_t)b*NS+q)*NHID + hh*NDK + d] = f2b(acc2[i][j][r]);
        }
      }
    }
}

// ---------------- K7: LN over bf16 h -> fp32 out (wave per row) --------------
__global__ __launch_bounds__(256) void ln2_kernel(
    const u16* __restrict__ h, const float* __restrict__ gamma,
    const float* __restrict__ beta, float* __restrict__ outp)
{
  const int t = threadIdx.x, wid = t>>6, lane = t&63;
  float g_[12], be_[12];
#pragma unroll
  for (int k=0;k<3;k++){               // 12 floats = 3 x float4
    float4 gg = *(const float4*)(gamma + lane*12 + k*4);
    float4 bb = *(const float4*)(beta  + lane*12 + k*4);
    g_[k*4+0]=gg.x; g_[k*4+1]=gg.y; g_[k*4+2]=gg.z; g_[k*4+3]=gg.w;
    be_[k*4+0]=bb.x; be_[k*4+1]=bb.y; be_[k*4+2]=bb.z; be_[k*4+3]=bb.w;
  }
  for (int row = blockIdx.x*4 + wid; row < NM; row += 1600*4){
    const u16* hr = h + (size_t)row*NHID + lane*12;
    u16x4 a0 = *(const u16x4*)hr;
    u16x4 a1 = *(const u16x4*)(hr+4);
    u16x4 a2 = *(const u16x4*)(hr+8);
    float v[12];
#pragma unroll
    for (int k=0;k<4;k++){
      v[k]   = b2f(a0[k]);
      v[4+k] = b2f(a1[k]);
      v[8+k] = b2f(a2[k]);
    }
    float s=0.f, q=0.f;
#pragma unroll
    for (int k=0;k<12;k++){ s+=v[k]; q+=v[k]*v[k]; }
#pragma unroll
    for (int m=1;m<64;m<<=1){ s+=__shfl_xor(s,m); q+=__shfl_xor(q,m); }
    const float mu = s*(1.0f/768.0f);
    const float rsv = rsqrtf(q*(1.0f/768.0f) - mu*mu + 1e-12f);
    float* orow = outp + (size_t)row*NHID + lane*12;
#pragma unroll
    for (int k=0;k<12;k++) orow[k] = (v[k]-mu)*rsv*g_[k] + be_[k];
  }
}

// -----------------------------------------------------------------------------
extern "C" void kernel_launch(void* const* d_in, const int* in_sizes, int n_in,
                              void* d_out, int out_size, void* d_ws, size_t ws_size,
                              hipStream_t stream)
{
  (void)in_sizes; (void)n_in; (void)out_size; (void)ws_size;
  const float* x    = (const float*)d_in[0];
  const float* mask = (const float*)d_in[1];
  const float* Wq   = (const float*)d_in[2];
  const float* bq   = (const float*)d_in[3];
  const float* Wk   = (const float*)d_in[4];
  const float* bk   = (const float*)d_in[5];
  const float* Wv   = (const float*)d_in[6];
  const float* bv   = (const float*)d_in[7];
  const float* We   = (const float*)d_in[8];
  const float* be   = (const float*)d_in[9];
  const float* Wf   = (const float*)d_in[10];
  const float* bf   = (const float*)d_in[11];
  const float* Wd   = (const float*)d_in[12];
  const float* bd   = (const float*)d_in[13];
  const float* gamma= (const float*)d_in[14];
  const float* beta = (const float*)d_in[15];

  float* out  = (float*)d_out;                    // [51200][768] fp32
  float* pout = out + (size_t)NM*NHID;            // [3072][200][64] fp32

  // ws layout (bytes):
  char* ws = (char*)d_ws;
  u16* xb    = (u16*)(ws);                        // 78,643,200 (written by yfe2)
  u16* yfe   = (u16*)(ws + 166723584ull);         // 50,331,648
  u16* kproj = (u16*)(ws + 217055232ull);         // 25,165,824
  u16* Wqb   = (u16*)(ws + 242221056ull);
  u16* Wkb   = (u16*)(ws + 243400704ull);
  u16* Wvb   = (u16*)(ws + 244580352ull);
  u16* Wdb   = (u16*)(ws + 245760000ull);
  u16* Wfeb  = (u16*)(ws + 246939648ull);         // 65,536 ([128][256])
  float* rsb = (float*)(ws + 247005184ull);       // 131,072
  u16* vprojT= (u16*)(ws + 247136256ull);         // 25,165,824
  u16* ctxb  = (u16*)(ws + 272302080ull);         // 78,643,200
  u16* hb    = (u16*)(ws + 350945280ull);         // 78,643,200

  prep_kernel<<<2304,256,0,stream>>>(Wq,Wk,Wv,Wd,Wf,We,mask,Wqb,Wkb,Wvb,Wdb,Wfeb,rsb);
  gemm_yfe2<<<dim3(NB,6),256,0,stream>>>(x,mask,Wfeb,yfe,xb);   // fused x->xb
  gemm_projkv<<<3072,256,0,stream>>>(yfe,Wkb,Wvb,rsb,bk,bv,bf,be,kproj,vprojT);
  attn2_kernel<<<3072,256,0,stream>>>(xb,Wqb,bq,kproj,vprojT,pout,ctxb);
  gemm_ring<<<600,512,0,stream>>>(ctxb,Wdb,bd,xb,hb);
  ln2_kernel<<<1600,256,0,stream>>>(hb,gamma,beta,out);
}

// Round 15
// 508.826 us; speedup vs baseline: 1.3178x; 1.3178x over previous
//
#include <hip/hip_runtime.h>
#include <stdint.h>

typedef unsigned short u16;
typedef short bf16x8 __attribute__((ext_vector_type(8)));
typedef float f32x4 __attribute__((ext_vector_type(4)));
typedef unsigned short u16x4 __attribute__((ext_vector_type(4)));

#define NB   256
#define NS   200
#define NHID 768
#define NHEAD 12
#define NDK  64
#define NK   64
#define NBH  (NB*NHEAD)   // 3072
#define NM   (NB*NS)      // 51200

__device__ __forceinline__ u16 f2b(float f){
  unsigned u = __builtin_bit_cast(unsigned, f);
  return (u16)((u + 0x7FFFu + ((u>>16)&1u)) >> 16);   // RNE, finite inputs
}
__device__ __forceinline__ float b2f(u16 b){
  return __builtin_bit_cast(float, (unsigned)b << 16);
}
__device__ __forceinline__ bf16x8 pack8(const float* v){
  bf16x8 r;
#pragma unroll
  for (int i=0;i<8;i++) r[i] = (short)f2b(v[i]);
  return r;
}
__device__ __forceinline__ f32x4 mfma16(bf16x8 a, bf16x8 b, f32x4 c){
  return __builtin_amdgcn_mfma_f32_16x16x32_bf16(a, b, c, 0, 0, 0);
}
__device__ __forceinline__ void gload16(u16* l, const u16* g){
  __builtin_amdgcn_global_load_lds(
      (const __attribute__((address_space(1))) void*)g,
      (__attribute__((address_space(3))) void*)l, 16, 0, 0);
}

// ---------------- K0: merged prep (pack W's, pack Wfe[128][256], rowsums) ----
__global__ __launch_bounds__(256) void prep_kernel(
    const float* __restrict__ Wq, const float* __restrict__ Wk,
    const float* __restrict__ Wv, const float* __restrict__ Wd,
    const float* __restrict__ Wf, const float* __restrict__ We,
    const float* __restrict__ mask,
    u16* __restrict__ Wqb, u16* __restrict__ Wkb,
    u16* __restrict__ Wvb, u16* __restrict__ Wdb,
    u16* __restrict__ Wfeb, float* __restrict__ rs)
{
  const int blk = blockIdx.x, t = threadIdx.x;
  const int i = blk*256 + t;            // grid 2304 -> 589824 exact
  Wqb[i]=f2b(Wq[i]); Wkb[i]=f2b(Wk[i]); Wvb[i]=f2b(Wv[i]); Wdb[i]=f2b(Wd[i]);
  if (blk < 128){                       // Wfe pack: row=blk, 256 cols (200 real)
    float v = 0.f;
    if (t < NS) v = (blk<64) ? Wf[blk*NS+t] : We[(blk-64)*NS+t];
    Wfeb[blk*256+t] = f2b(v);
  }
  if (blk >= 1024 && blk < 1280 && t < 128){  // rowsums: b=blk-1024, kk=t
    const int b = blk-1024;
    const float* src = (t<64) ? (Wf + t*NS) : (We + (t-64)*NS);
    float acc = 0.f;
    for (int s=0;s<NS;s++) acc += src[s]*mask[b*NS+s];
    rs[b*128+t] = acc;
  }
}

// ---------------- K2: yfe = Wfe_masked @ x[b]^T, FUSED x->xb convert ---------
__global__ __launch_bounds__(256) void gemm_yfe2(
    const float* __restrict__ x, const float* __restrict__ mask,
    const u16* __restrict__ Wfeb, u16* __restrict__ yfe,
    u16* __restrict__ xb)
{
  __shared__ u16 Al[128*64];     // A K-slice, ld=64
  __shared__ u16 Bl[128*72];     // B K-slice, ld=72, swizzled
  __shared__ float Ml[256];      // mask row, zero-extended
  const int t=threadIdx.x, w=t>>6, lane=t&63, hi=lane>>4, lo=lane&15;
  const int sr=lane>>3, sc=lane&7;
  const int b=blockIdx.x, col0=blockIdx.y*128;
  const int a16 = t&15, q4 = t>>4;
  const int ss0 = q4*4;
  const int swzw = (a16&7)<<3;

  Ml[t] = (t<NS) ? mask[b*NS+t] : 0.f;

  f32x4 acc[4][4];
#pragma unroll
  for(int i=0;i<4;i++)
#pragma unroll
    for(int j=0;j<4;j++) acc[i][j]=(f32x4)0.0f;

  const u16* Ab=&Al[((w>>1)*64+lo)*64 + hi*8];
  int nb_[4], sw_[4];
#pragma unroll
  for (int j=0;j<4;j++){
    const int n = (w&1)*64 + j*16 + lo;
    nb_[j] = n*72;
    sw_[j] = ((n>>3)&7)<<3;
  }
  __syncthreads();   // Ml visible

  for (int kt=0; kt<256; kt+=64){
#pragma unroll
    for (int i8=0;i8<4;i8++){
      const int r = w*32 + i8*8 + sr;
      gload16(&Al[r*64 + sc*8], Wfeb + (size_t)r*256 + kt + sc*8);
    }
    float vv[4][8];
#pragma unroll
    for (int ii=0;ii<4;ii++){
      const int s = kt + ss0 + ii;
      const int srow = (s<NS) ? s : (NS-1);
      const float* gp = x + ((size_t)b*NS + srow)*NHID + col0 + a16*8;
      float4 u0 = *(const float4*)gp, u1 = *(const float4*)(gp+4);
      if (s < NS){
        float tu[8] = {u0.x,u0.y,u0.z,u0.w,u1.x,u1.y,u1.z,u1.w};
        *(bf16x8*)(xb + ((size_t)b*NS + s)*NHID + col0 + a16*8) = pack8(tu);
      }
      const float m = Ml[s];
      vv[ii][0]=u0.x*m; vv[ii][1]=u0.y*m; vv[ii][2]=u0.z*m; vv[ii][3]=u0.w*m;
      vv[ii][4]=u1.x*m; vv[ii][5]=u1.y*m; vv[ii][6]=u1.z*m; vv[ii][7]=u1.w*m;
    }
    const int ss_swz = ss0 ^ swzw;
#pragma unroll
    for (int h=0;h<8;h++){
      u16x4 p;
      p[0]=f2b(vv[0][h]); p[1]=f2b(vv[1][h]);
      p[2]=f2b(vv[2][h]); p[3]=f2b(vv[3][h]);
      *(u16x4*)&Bl[(a16*8+h)*72 + ss_swz] = p;
    }
    asm volatile("s_waitcnt vmcnt(0)" ::: "memory");
    __syncthreads();
#pragma unroll
    for (int ks=0; ks<2; ks++){
      bf16x8 a[4], bfr[4];
#pragma unroll
      for (int i=0;i<4;i++) a[i]   = *(const bf16x8*)(Ab + i*16*64 + ks*32);
#pragma unroll
      for (int j=0;j<4;j++){
        const int s8 = ks*32 + hi*8;
        bfr[j] = *(const bf16x8*)&Bl[nb_[j] + (s8 ^ sw_[j])];
      }
#pragma unroll
      for (int i=0;i<4;i++)
#pragma unroll
        for (int j=0;j<4;j++) acc[i][j] = mfma16(a[i], bfr[j], acc[i][j]);
    }
    __syncthreads();
  }
  const int mbase=(w>>1)*64, nbase=col0+(w&1)*64;
#pragma unroll
  for (int i=0;i<4;i++)
#pragma unroll
    for (int r=0;r<4;r++){
      const int m = mbase + i*16 + hi*4 + r;
#pragma unroll
      for (int j=0;j<4;j++){
        const int n = nbase + j*16 + lo;
        yfe[(size_t)b*98304 + (size_t)m*NHID + n] = f2b(acc[i][j][r]);
      }
    }
}

// ---------------- ring GEMM: C = A @ B^T, M=51200, N=768 ---------------------
// BM=256, BN=256, BK=32, 4-slot LDS ring, 512 thr, 8 waves (2M x 4N).
// 1-D grid 600, XCD-swizzled: row=(bid/24)*8+bid%8, col=(bid/8)%3.
// EPI=0: q bf16 row-major [m][n] + bias.  EPI=1: h bf16 = acc + bias + resid.
template<int EPI>
__global__ __launch_bounds__(512, 2) void gemm_ring(
    const u16* __restrict__ Ag_, const u16* __restrict__ Bg_,
    const float* __restrict__ bias, const u16* __restrict__ resid,
    u16* __restrict__ Cout)
{
  __shared__ u16 AS[4][8192];
  __shared__ u16 BS[4][8192];
  const int t = threadIdx.x;
  const int w = t>>6, lane = t&63, hi = lane>>4, lo = lane&15;
  const int wm = w>>2, wn = w&3;
  const int bid = blockIdx.x;
  const int row0 = ((bid/24)*8 + (bid&7))*256;    // bijective: 600 = 25*24
  const int col0 = ((bid>>3)%3)*256;
  const u16* Ag = Ag_ + (size_t)row0*NHID;
  const u16* Bg = Bg_ + (size_t)col0*NHID;
  const int rp0 = t>>3, cc = t&7;

  f32x4 acc[8][4];
#pragma unroll
  for (int i=0;i<8;i++)
#pragma unroll
    for (int j=0;j<4;j++) acc[i][j] = (f32x4)0.0f;

  int aoff[8], boff[4];
#pragma unroll
  for (int i=0;i<8;i++){
    const int r = wm*128 + i*16 + lo;
    const int rp = r>>1, c = (r&1)*4 + hi;
    aoff[i] = rp*64 + ((c ^ (rp&7))<<3);
  }
#pragma unroll
  for (int j=0;j<4;j++){
    const int n = wn*64 + j*16 + lo;
    const int rp = n>>1, c = (n&1)*4 + hi;
    boff[j] = rp*64 + ((c ^ (rp&7))<<3);
  }

  auto stage = [&](int s, int kt){
#pragma unroll
    for (int i8=0;i8<2;i8++){
      const int rp = i8*64 + rp0;
      const int c  = cc ^ (rp&7);
      const int grow = rp*2 + (c>>2);
      const int gcol = (c&3)<<3;
      gload16(&AS[s][rp*64 + cc*8], Ag + (size_t)grow*NHID + kt + gcol);
      gload16(&BS[s][rp*64 + cc*8], Bg + (size_t)grow*NHID + kt + gcol);
    }
  };
  auto body = [&](const u16* as_, const u16* bs_){
    bf16x8 av[8], bvv[4];
#pragma unroll
    for (int j=0;j<4;j++) bvv[j] = *(const bf16x8*)(bs_ + boff[j]);
#pragma unroll
    for (int i=0;i<8;i++) av[i] = *(const bf16x8*)(as_ + aoff[i]);
    __builtin_amdgcn_s_setprio(1);
#pragma unroll
    for (int i=0;i<8;i++)
#pragma unroll
      for (int j=0;j<4;j++) acc[i][j] = mfma16(av[i], bvv[j], acc[i][j]);
    __builtin_amdgcn_s_setprio(0);
  };
  auto step = [&](int tt, int s){
    if (tt+3 < 24) stage((s+3)&3, (tt+3)*32);
    body(AS[s], BS[s]);
    if (tt <= 20)      { asm volatile("s_waitcnt vmcnt(8)" ::: "memory"); }
    else if (tt == 21) { asm volatile("s_waitcnt vmcnt(4)" ::: "memory"); }
    else if (tt == 22) { asm volatile("s_waitcnt vmcnt(0)" ::: "memory"); }
    if (tt < 23){
      __builtin_amdgcn_sched_barrier(0);
      asm volatile("s_barrier" ::: "memory");
      __builtin_amdgcn_sched_barrier(0);
    }
  };

  stage(0,0); stage(1,32); stage(2,64);
  asm volatile("s_waitcnt vmcnt(8)" ::: "memory");
  asm volatile("s_barrier" ::: "memory");
  __builtin_amdgcn_sched_barrier(0);

#pragma unroll
  for (int tt=0; tt<24; tt+=4){
    step(tt,0); step(tt+1,1); step(tt+2,2); step(tt+3,3);
  }

#pragma unroll
  for (int i=0;i<8;i++)
#pragma unroll
    for (int q=0;q<4;q++){
      const int m = row0 + wm*128 + i*16 + hi*4 + q;
#pragma unroll
      for (int j=0;j<4;j++){
        const int n = col0 + wn*64 + j*16 + lo;
        float v = acc[i][j][q] + bias[n];
        const size_t gi = (size_t)m*NHID + n;
        if constexpr (EPI==0){
          Cout[gi] = f2b(v);                       // q row-major [m][h*64+d]
        } else {
          Cout[gi] = f2b(v + b2f(resid[gi]));
        }
      }
    }
}

// ---------------- K4: merged kproj (z=0) / vprojT (z=1) ----------------------
// 1-D grid 3072, XCD-swizzled: b=(bid/96)*8+bid%8, j=(bid/8)%12, col=j%6,
// z=j/6 -> all 12 blocks of a b share the XCD so yfe[b] (192KB) is L2-shared.
__global__ __launch_bounds__(256) void gemm_projkv(
    const u16* __restrict__ yfe, const u16* __restrict__ Wkb,
    const u16* __restrict__ Wvb, const float* __restrict__ rs,
    const float* __restrict__ bk, const float* __restrict__ bv,
    const float* __restrict__ bff, const float* __restrict__ bee,
    u16* __restrict__ kproj, u16* __restrict__ vout)
{
  __shared__ u16 S[192*64];
  const int t=threadIdx.x, w=t>>6, lane=t&63, hi=lane>>4, lo=lane&15;
  const int sr=lane>>3, sc=lane&7;
  const int bid=blockIdx.x;
  const int b = (bid/96)*8 + (bid&7);             // bijective: 3072 = 32*96
  const int jj = (bid>>3)%12;
  const int colb = jj%6, z = jj/6;

  if (z==0){
    u16* Al = S;                 // 64x64
    u16* Bl = S + 64*64;         // 128x64
    const int col0=colb*128;
    const u16* yf = yfe + (size_t)b*98304;
    f32x4 acc[2][4];
#pragma unroll
    for(int i=0;i<2;i++)
#pragma unroll
      for(int j=0;j<4;j++) acc[i][j]=(f32x4)0.0f;
    const u16* Ab=&Al[((w>>1)*32+lo)*64 + hi*8];
    const u16* Bb=&Bl[((w&1)*64+lo)*64 + hi*8];
    for (int kt=0; kt<NHID; kt+=64){
#pragma unroll
      for (int i8=0;i8<2;i8++){
        const int r = w*16 + i8*8 + sr;
        gload16(&Al[r*64 + sc*8], yf + (size_t)r*NHID + kt + sc*8);
      }
#pragma unroll
      for (int i8=0;i8<4;i8++){
        const int r = w*32 + i8*8 + sr;
        gload16(&Bl[r*64 + sc*8], Wkb + (size_t)(col0+r)*NHID + kt + sc*8);
      }
      asm volatile("s_waitcnt vmcnt(0)" ::: "memory");
      __syncthreads();
#pragma unroll
      for (int ks=0; ks<2; ks++){
        bf16x8 a[2], bfr[4];
#pragma unroll
        for (int i=0;i<2;i++) a[i]   = *(const bf16x8*)(Ab + i*16*64 + ks*32);
#pragma unroll
        for (int j=0;j<4;j++) bfr[j] = *(const bf16x8*)(Bb + j*16*64 + ks*32);
#pragma unroll
        for (int i=0;i<2;i++)
#pragma unroll
          for (int j=0;j<4;j++) acc[i][j] = mfma16(a[i], bfr[j], acc[i][j]);
      }
      __syncthreads();
    }
    const int mbase=(w>>1)*32, nbase=col0+(w&1)*64;
#pragma unroll
    for (int i=0;i<2;i++)
#pragma unroll
      for (int r=0;r<4;r++){
        const int m = mbase + i*16 + hi*4 + r;          // kk
        const float rsv = rs[b*128 + m], bfv = bff[m];
#pragma unroll
        for (int j=0;j<4;j++){
          const int n = nbase + j*16 + lo;              // hd
          kproj[(size_t)b*49152 + (size_t)m*NHID + n] = f2b(acc[i][j][r] + rsv*bk[n] + bfv);
        }
      }
  } else {
    u16* Al = S;                 // 128x64
    u16* Bl = S + 128*64;        // 64x64
    const int row0=colb*128;
    const u16* ye = yfe + (size_t)b*98304 + 49152;
    f32x4 acc[4][2];
#pragma unroll
    for(int i=0;i<4;i++)
#pragma unroll
      for(int j=0;j<2;j++) acc[i][j]=(f32x4)0.0f;
    const u16* Ab=&Al[((w>>1)*64+lo)*64 + hi*8];
    const u16* Bb=&Bl[((w&1)*32+lo)*64 + hi*8];
    for (int kt=0; kt<NHID; kt+=64){
#pragma unroll
      for (int i8=0;i8<4;i8++){
        const int r = w*32 + i8*8 + sr;
        gload16(&Al[r*64 + sc*8], Wvb + (size_t)(row0+r)*NHID + kt + sc*8);
      }
#pragma unroll
      for (int i8=0;i8<2;i8++){
        const int r = w*16 + i8*8 + sr;
        gload16(&Bl[r*64 + sc*8], ye + (size_t)r*NHID + kt + sc*8);
      }
      asm volatile("s_waitcnt vmcnt(0)" ::: "memory");
      __syncthreads();
#pragma unroll
      for (int ks=0; ks<2; ks++){
        bf16x8 a[4], bfr[2];
#pragma unroll
        for (int i=0;i<4;i++) a[i]   = *(const bf16x8*)(Ab + i*16*64 + ks*32);
#pragma unroll
        for (int j=0;j<2;j++) bfr[j] = *(const bf16x8*)(Bb + j*16*64 + ks*32);
#pragma unroll
        for (int i=0;i<4;i++)
#pragma unroll
          for (int j=0;j<2;j++) acc[i][j] = mfma16(a[i], bfr[j], acc[i][j]);
      }
      __syncthreads();
    }
    const int mbase=row0+(w>>1)*64, nbase=(w&1)*32;
#pragma unroll
    for (int i=0;i<4;i++)
#pragma unroll
      for (int r=0;r<4;r++){
        const int m = mbase + i*16 + hi*4 + r;          // hd
        const float bvv = bv[m];
#pragma unroll
        for (int j=0;j<2;j++){
          const int n = nbase + j*16 + lo;              // kk
          vout[(size_t)b*49152 + (size_t)m*64 + n] = f2b(acc[i][j][r] + rs[b*128+64+n]*bvv + bee[n]);
        }
      }
  }
}

// ---------------- K5: fused attention per (b,h) ------------------------------
__global__ __launch_bounds__(256) void attn_kernel(
    const u16* __restrict__ qb,      // [B*S][768] row-major (h*64+d cols)
    const u16* __restrict__ kproj,   // [B][64][768]  ([kk][h*64+d])
    const u16* __restrict__ vprojT,  // [B][768][64]  ([h*64+d][kk])
    float* __restrict__ pout,        // [BH][200][64] fp32
    u16* __restrict__ ctxb)          // [B][200][768] bf16
{
  __shared__ u16 QL[208*72];   // q tile (rows 200..207 zero); reused as P
  __shared__ u16 KP[64*72];
  __shared__ u16 VP[64*72];
  const int t=threadIdx.x, w=t>>6, lane=t&63, hi=lane>>4, lo=lane&15;
  const int bh = blockIdx.x, b=bh/NHEAD, hh=bh%NHEAD;
  for (int c=t;c<1600;c+=256){
    const int row=c>>3, col8=(c&7)*8;
    *(bf16x8*)&QL[row*72+col8] =
      *(const bf16x8*)(qb + ((size_t)(b*NS+row))*NHID + hh*64 + col8);
  }
  if (t<72){ const int row=200+t/9, col8=(t%9)*8; *(bf16x8*)&QL[row*72+col8]=(bf16x8)0; }
  for (int c=t;c<512;c+=256){
    const int row=c>>3, col8=(c&7)*8;
    *(bf16x8*)&KP[row*72+col8] = *(const bf16x8*)(kproj  + (size_t)b*49152 + (size_t)row*NHID + hh*64 + col8);
    *(bf16x8*)&VP[row*72+col8] = *(const bf16x8*)(vprojT + (size_t)b*49152 + (size_t)(hh*64+row)*64 + col8);
  }
  __syncthreads();
  const int mf0 = (w==0)?0:(1+w*3);
  const int nmf = (w==0)?4:3;
  f32x4 acc[4][4];
#pragma unroll
  for(int i=0;i<4;i++)
#pragma unroll
    for(int j=0;j<4;j++) acc[i][j]=(f32x4)0.0f;
#pragma unroll
  for (int ks=0; ks<2; ks++){
    bf16x8 a[4], bb[4];
#pragma unroll
    for (int j=0;j<4;j++) bb[j]=*(const bf16x8*)&KP[(j*16+lo)*72 + ks*32 + hi*8];
#pragma unroll
    for (int i=0;i<4;i++) if (i<nmf) a[i]=*(const bf16x8*)&QL[((mf0+i)*16+lo)*72 + ks*32 + hi*8];
#pragma unroll
    for (int i=0;i<4;i++) if (i<nmf)
#pragma unroll
      for (int j=0;j<4;j++)
        acc[i][j]=mfma16(a[i],bb[j],acc[i][j]);
  }
  __syncthreads();

#pragma unroll
  for (int i=0;i<4;i++) if (i<nmf){
#pragma unroll
    for (int r=0;r<4;r++){
      const int q = (mf0+i)*16 + hi*4 + r;
      float s0=acc[i][0][r]*0.125f, s1=acc[i][1][r]*0.125f,
            s2=acc[i][2][r]*0.125f, s3=acc[i][3][r]*0.125f;
      float mx=fmaxf(fmaxf(s0,s1),fmaxf(s2,s3));
      mx=fmaxf(mx,__shfl_xor(mx,1)); mx=fmaxf(mx,__shfl_xor(mx,2));
      mx=fmaxf(mx,__shfl_xor(mx,4)); mx=fmaxf(mx,__shfl_xor(mx,8));
      float e0=__expf(s0-mx), e1=__expf(s1-mx), e2=__expf(s2-mx), e3=__expf(s3-mx);
      float sm=e0+e1+e2+e3;
      sm+=__shfl_xor(sm,1); sm+=__shfl_xor(sm,2); sm+=__shfl_xor(sm,4); sm+=__shfl_xor(sm,8);
      const float inv=1.0f/sm;
      const float p0=e0*inv,p1=e1*inv,p2=e2*inv,p3=e3*inv;
      if (q<NS){
        float* pg = pout + ((size_t)bh*NS + q)*NK + lo;
        pg[0]=p0; pg[16]=p1; pg[32]=p2; pg[48]=p3;
      }
      u16* pl = &QL[q*72 + lo];
      pl[0]=f2b(p0); pl[16]=f2b(p1); pl[32]=f2b(p2); pl[48]=f2b(p3);
    }
  }
  f32x4 acc2[4][4];
#pragma unroll
  for(int i=0;i<4;i++)
#pragma unroll
    for(int j=0;j<4;j++) acc2[i][j]=(f32x4)0.0f;
#pragma unroll
  for (int ks=0; ks<2; ks++){
    bf16x8 a[4], bb[4];
#pragma unroll
    for (int j=0;j<4;j++) bb[j]=*(const bf16x8*)&VP[(j*16+lo)*72 + ks*32 + hi*8];
#pragma unroll
    for (int i=0;i<4;i++) if (i<nmf) a[i]=*(const bf16x8*)&QL[((mf0+i)*16+lo)*72 + ks*32 + hi*8];
#pragma unroll
    for (int i=0;i<4;i++) if (i<nmf)
#pragma unroll
      for (int j=0;j<4;j++)
        acc2[i][j]=mfma16(a[i],bb[j],acc2[i][j]);
  }
#pragma unroll
  for (int i=0;i<4;i++) if (i<nmf)
#pragma unroll
    for (int r=0;r<4;r++){
      const int q=(mf0+i)*16+hi*4+r;
      if (q<NS){
#pragma unroll
        for (int j=0;j<4;j++){
          const int d=j*16+lo;
          ctxb[((size_t)b*NS+q)*NHID + hh*NDK + d] = f2b(acc2[i][j][r]);
        }
      }
    }
}

// ---------------- K7: LN over bf16 h -> fp32 out (wave per row) --------------
__global__ __launch_bounds__(256) void ln2_kernel(
    const u16* __restrict__ h, const float* __restrict__ gamma,
    const float* __restrict__ beta, float* __restrict__ outp)
{
  const int t = threadIdx.x, wid = t>>6, lane = t&63;
  float g_[12], be_[12];
#pragma unroll
  for (int k=0;k<3;k++){               // 12 floats = 3 x float4
    float4 gg = *(const float4*)(gamma + lane*12 + k*4);
    float4 bb = *(const float4*)(beta  + lane*12 + k*4);
    g_[k*4+0]=gg.x; g_[k*4+1]=gg.y; g_[k*4+2]=gg.z; g_[k*4+3]=gg.w;
    be_[k*4+0]=bb.x; be_[k*4+1]=bb.y; be_[k*4+2]=bb.z; be_[k*4+3]=bb.w;
  }
  for (int row = blockIdx.x*4 + wid; row < NM; row += 1600*4){
    const u16* hr = h + (size_t)row*NHID + lane*12;
    u16x4 a0 = *(const u16x4*)hr;
    u16x4 a1 = *(const u16x4*)(hr+4);
    u16x4 a2 = *(const u16x4*)(hr+8);
    float v[12];
#pragma unroll
    for (int k=0;k<4;k++){
      v[k]   = b2f(a0[k]);
      v[4+k] = b2f(a1[k]);
      v[8+k] = b2f(a2[k]);
    }
    float s=0.f, q=0.f;
#pragma unroll
    for (int k=0;k<12;k++){ s+=v[k]; q+=v[k]*v[k]; }
#pragma unroll
    for (int m=1;m<64;m<<=1){ s+=__shfl_xor(s,m); q+=__shfl_xor(q,m); }
    const float mu = s*(1.0f/768.0f);
    const float rsv = rsqrtf(q*(1.0f/768.0f) - mu*mu + 1e-12f);
    float* orow = outp + (size_t)row*NHID + lane*12;
#pragma unroll
    for (int k=0;k<12;k++) orow[k] = (v[k]-mu)*rsv*g_[k] + be_[k];
  }
}

// -----------------------------------------------------------------------------
extern "C" void kernel_launch(void* const* d_in, const int* in_sizes, int n_in,
                              void* d_out, int out_size, void* d_ws, size_t ws_size,
                              hipStream_t stream)
{
  (void)in_sizes; (void)n_in; (void)out_size; (void)ws_size;
  const float* x    = (const float*)d_in[0];
  const float* mask = (const float*)d_in[1];
  const float* Wq   = (const float*)d_in[2];
  const float* bq   = (const float*)d_in[3];
  const float* Wk   = (const float*)d_in[4];
  const float* bk   = (const float*)d_in[5];
  const float* Wv   = (const float*)d_in[6];
  const float* bv   = (const float*)d_in[7];
  const float* We   = (const float*)d_in[8];
  const float* be   = (const float*)d_in[9];
  const float* Wf   = (const float*)d_in[10];
  const float* bf   = (const float*)d_in[11];
  const float* Wd   = (const float*)d_in[12];
  const float* bd   = (const float*)d_in[13];
  const float* gamma= (const float*)d_in[14];
  const float* beta = (const float*)d_in[15];

  float* out  = (float*)d_out;                    // [51200][768] fp32
  float* pout = out + (size_t)NM*NHID;            // [3072][200][64] fp32

  // ws layout (bytes), peak use ~430 MB:
  char* ws = (char*)d_ws;
  u16* xb    = (u16*)(ws);                        // 78,643,200 (written by yfe2)
  u16* qb    = (u16*)(ws + 78643200ull);          // 78,643,200 (row-major q)
  u16* yfe   = (u16*)(ws + 166723584ull);         // 50,331,648
  u16* kproj = (u16*)(ws + 217055232ull);         // 25,165,824
  u16* Wqb   = (u16*)(ws + 242221056ull);
  u16* Wkb   = (u16*)(ws + 243400704ull);
  u16* Wvb   = (u16*)(ws + 244580352ull);
  u16* Wdb   = (u16*)(ws + 245760000ull);
  u16* Wfeb  = (u16*)(ws + 246939648ull);         // 65,536 ([128][256])
  float* rsb = (float*)(ws + 247005184ull);       // 131,072
  u16* vprojT= (u16*)(ws + 247136256ull);         // 25,165,824
  u16* ctxb  = (u16*)(ws + 272302080ull);         // 78,643,200
  u16* hb    = (u16*)(ws + 350945280ull);         // 78,643,200

  prep_kernel<<<2304,256,0,stream>>>(Wq,Wk,Wv,Wd,Wf,We,mask,Wqb,Wkb,Wvb,Wdb,Wfeb,rsb);
  gemm_yfe2<<<dim3(NB,6),256,0,stream>>>(x,mask,Wfeb,yfe,xb);   // fused x->xb
  gemm_ring<0><<<600,512,0,stream>>>(xb,Wqb,bq,nullptr,qb);
  gemm_projkv<<<3072,256,0,stream>>>(yfe,Wkb,Wvb,rsb,bk,bv,bf,be,kproj,vprojT);
  attn_kernel<<<NBH,256,0,stream>>>(qb,kproj,vprojT,pout,ctxb);
  gemm_ring<1><<<600,512,0,stream>>>(ctxb,Wdb,bd,xb,hb);
  ln2_kernel<<<1600,256,0,stream>>>(hb,gamma,beta,out);
}